// Round 1
// baseline (196.471 us; speedup 1.0000x reference)
//
#include <hip/hip_runtime.h>

#define BATCH   65536
#define EMB     64
#define NREL    100
#define NCHUNK  8
#define CHUNK   (BATCH / NCHUNK)   // 8192

// One wave (64 threads) per block. blockIdx.y = relation, blockIdx.x = chunk.
// Phase 1: ballot-compact the chunk's batch indices matching this relation
//          into an LDS list (deterministic, no atomics).
// Phase 2: process matches 64 at a time, lane = batch element.
//          d = h_emb - t_emb staged per-lane in LDS (stride 67, conflict-free);
//          P rows are wave-uniform loads -> SGPRs -> v_fmac with SGPR operand.
// score[b] = sum_r ( sum_e (h[e]-t[e]) * P[e][r] + remb[r] )^2
__launch_bounds__(64)
__global__ void transr_kernel(const int* __restrict__ head,
                              const int* __restrict__ relation,
                              const int* __restrict__ tail,
                              const float* __restrict__ ent,
                              const float* __restrict__ remb,
                              const float* __restrict__ proj,
                              float* __restrict__ out) {
    __shared__ int   list[CHUNK];        // worst-case capacity: whole chunk
    __shared__ float dstage[64 * 67];    // per-lane d row, stride 67 (no bank conflict)
    __shared__ float remb_s[64];

    const int lane = threadIdx.x;        // 0..63
    const int rel  = blockIdx.y;         // 0..99
    const int base = blockIdx.x * CHUNK;

    remb_s[lane] = remb[rel * 64 + lane];

    // ---- Phase 1: scan chunk, compact matching indices (ballot, deterministic)
    int cnt = 0;
    const int4* rel4 = (const int4*)(relation + base);
    for (int it = 0; it < CHUNK / 256; ++it) {
        int4 v = rel4[it * 64 + lane];
        int vals[4] = {v.x, v.y, v.z, v.w};
        #pragma unroll
        for (int k = 0; k < 4; ++k) {
            bool m = (vals[k] == rel);
            unsigned long long mask = __ballot(m);
            if (m) {
                int rank = __popcll(mask & ((1ull << lane) - 1ull));
                list[cnt + rank] = base + (it * 64 + lane) * 4 + k;
            }
            cnt += __popcll(mask);
        }
    }
    __syncthreads();   // order LDS writes (list, remb_s) before cross-lane reads

    // ---- Phase 2: batches of 64 elements, lane = element
    const int nb = (cnt + 63) >> 6;
    const float* P = proj + (size_t)rel * 4096;

    for (int bb = 0; bb < nb; ++bb) {
        const int j  = (bb << 6) + lane;
        const int jj = (j < cnt) ? j : (cnt - 1);
        const int b  = list[jj];
        const int h  = head[b];
        const int t  = tail[b];

        // stage d = h_row - t_row into LDS (lane-private row)
        const float4* h4 = (const float4*)(ent + (size_t)h * 64);
        const float4* t4 = (const float4*)(ent + (size_t)t * 64);
        #pragma unroll
        for (int k = 0; k < 16; ++k) {
            float4 a = h4[k], c = t4[k];
            dstage[lane * 67 + 4 * k + 0] = a.x - c.x;
            dstage[lane * 67 + 4 * k + 1] = a.y - c.y;
            dstage[lane * 67 + 4 * k + 2] = a.z - c.z;
            dstage[lane * 67 + 4 * k + 3] = a.w - c.w;
        }

        float acc[64];
        #pragma unroll
        for (int r = 0; r < 64; ++r) acc[r] = 0.f;

        #pragma unroll 2
        for (int e = 0; e < 64; ++e) {
            const float de = dstage[lane * 67 + e];       // lane-private LDS read
            const float* Pe = P + (e << 6);               // wave-uniform -> s_load
            #pragma unroll
            for (int r = 0; r < 64; ++r)
                acc[r] = fmaf(de, Pe[r], acc[r]);
        }

        // epilogue: score = sum_r (acc[r] + remb[r])^2, 4 partial chains for ILP
        float s0 = 0.f, s1 = 0.f, s2 = 0.f, s3 = 0.f;
        #pragma unroll
        for (int r = 0; r < 64; r += 4) {
            float v0 = acc[r + 0] + remb_s[r + 0];
            float v1 = acc[r + 1] + remb_s[r + 1];
            float v2 = acc[r + 2] + remb_s[r + 2];
            float v3 = acc[r + 3] + remb_s[r + 3];
            s0 = fmaf(v0, v0, s0);
            s1 = fmaf(v1, v1, s1);
            s2 = fmaf(v2, v2, s2);
            s3 = fmaf(v3, v3, s3);
        }
        if (j < cnt) out[b] = (s0 + s1) + (s2 + s3);
    }
}

extern "C" void kernel_launch(void* const* d_in, const int* in_sizes, int n_in,
                              void* d_out, int out_size, void* d_ws, size_t ws_size,
                              hipStream_t stream) {
    const int*   head     = (const int*)d_in[0];
    const int*   relation = (const int*)d_in[1];
    const int*   tail     = (const int*)d_in[2];
    const float* ent      = (const float*)d_in[3];
    const float* remb     = (const float*)d_in[4];
    const float* proj     = (const float*)d_in[5];
    float*       out      = (float*)d_out;

    dim3 grid(NCHUNK, NREL);
    transr_kernel<<<grid, 64, 0, stream>>>(head, relation, tail, ent, remb, proj, out);
}

// Round 2
// 29.720 us; speedup vs baseline: 6.6107x; 6.6107x over previous
//
#include <hip/hip_runtime.h>

#define BATCH   65536
#define NREL    100
#define NCHUNK  16
#define CHUNK   (BATCH / NCHUNK)   // 4096
#define DSTRIDE 65                 // odd stride -> conflict-free lane-private rows

// Grid (NCHUNK, NREL), 256 threads = 4 waves per block.
// Phase 1: 4 waves ballot-compact their chunk segment's matches into an LDS
//          list (LDS-atomic slot allocation; order-independent per-element math).
// Phase 2: one 64-element batch at a time. 256 threads cooperatively gather
//          d = h_emb - t_emb into dstage (stride 65). Then each wave computes
//          a 16-column quarter: acc[r] += d[e] * P[e][r], P rows via
//          s_load_dwordx16 (wave-uniform base via readfirstlane), remb folded
//          into acc init. Partials combined through LDS, wave 0 writes out.
__launch_bounds__(256)
__global__ void transr_kernel(const int* __restrict__ head,
                              const int* __restrict__ relation,
                              const int* __restrict__ tail,
                              const float* __restrict__ ent,
                              const float* __restrict__ remb,
                              const float* __restrict__ proj,
                              float* __restrict__ out) {
    __shared__ unsigned short list[CHUNK];     // chunk-local indices (<4096)
    __shared__ float dstage[64 * DSTRIDE];
    __shared__ float psum[4][64];
    __shared__ int cnt_s;

    const int tid  = threadIdx.x;
    const int wid  = tid >> 6;
    const int lane = tid & 63;
    const int rel  = blockIdx.y;
    const int base = blockIdx.x * CHUNK;

    if (tid == 0) cnt_s = 0;
    __syncthreads();

    // ---- Phase 1: parallel ballot compaction (4 waves, disjoint segments)
    {
        const int seg = wid * (CHUNK / 4);                    // 1024 elems/wave
        const int4* rel4 = (const int4*)(relation + base + seg);
        #pragma unroll
        for (int it = 0; it < CHUNK / 4 / 256; ++it) {        // 4 iterations
            int4 v = rel4[it * 64 + lane];
            int vals[4] = {v.x, v.y, v.z, v.w};
            #pragma unroll
            for (int k = 0; k < 4; ++k) {
                bool m = (vals[k] == rel);
                unsigned long long mask = __ballot(m);
                int nm = __popcll(mask);
                int pos = 0;
                if (lane == 0 && nm) pos = atomicAdd(&cnt_s, nm);
                pos = __shfl(pos, 0);
                if (m) {
                    int rank = __popcll(mask & ((1ull << lane) - 1ull));
                    list[pos + rank] =
                        (unsigned short)(seg + (it * 64 + lane) * 4 + k);
                }
            }
        }
    }
    __syncthreads();
    const int cnt = cnt_s;
    const int nb  = (cnt + 63) >> 6;

    // wave-uniform scalar bases (readfirstlane -> guaranteed s_load path)
    const int coloff = __builtin_amdgcn_readfirstlane(wid << 4);
    const float* Pq  = proj + (size_t)rel * 4096 + coloff;
    const float* Rq  = remb + rel * 64 + coloff;
    float rinit[16];
    #pragma unroll
    for (int r = 0; r < 16; ++r) rinit[r] = Rq[r];

    for (int bb = 0; bb < nb; ++bb) {
        // ---- cooperative gather: thread = (elem = tid>>2, quarter = tid&3)
        {
            const int elem = tid >> 2, q = tid & 3;
            int j  = bb * 64 + elem;
            int jj = (j < cnt) ? j : (cnt - 1);
            int b  = base + list[jj];
            int h  = head[b], t = tail[b];
            const float4* h4 = (const float4*)(ent + (size_t)h * 64) + q * 4;
            const float4* t4 = (const float4*)(ent + (size_t)t * 64) + q * 4;
            #pragma unroll
            for (int k = 0; k < 4; ++k) {
                float4 a = h4[k], c = t4[k];
                float* ds = &dstage[elem * DSTRIDE + q * 16 + k * 4];
                ds[0] = a.x - c.x; ds[1] = a.y - c.y;
                ds[2] = a.z - c.z; ds[3] = a.w - c.w;
            }
        }
        __syncthreads();

        // ---- each wave: 16-column quarter of the 64x64 matvec
        float acc[16];
        #pragma unroll
        for (int r = 0; r < 16; ++r) acc[r] = rinit[r];

        #pragma unroll 4
        for (int e = 0; e < 64; ++e) {
            float de = dstage[lane * DSTRIDE + e];   // conflict-free (stride 65)
            const float* Pe = Pq + (e << 6);         // wave-uniform -> s_load_dwordx16
            #pragma unroll
            for (int r = 0; r < 16; ++r) acc[r] = fmaf(de, Pe[r], acc[r]);
        }

        float s0 = 0.f, s1 = 0.f;
        #pragma unroll
        for (int r = 0; r < 16; r += 2) {
            s0 = fmaf(acc[r], acc[r], s0);
            s1 = fmaf(acc[r + 1], acc[r + 1], s1);
        }
        psum[wid][lane] = s0 + s1;
        __syncthreads();

        if (wid == 0) {
            int j = bb * 64 + lane;
            if (j < cnt) {
                int b = base + list[j];
                out[b] = (psum[0][lane] + psum[1][lane]) +
                         (psum[2][lane] + psum[3][lane]);
            }
        }
    }
}

extern "C" void kernel_launch(void* const* d_in, const int* in_sizes, int n_in,
                              void* d_out, int out_size, void* d_ws, size_t ws_size,
                              hipStream_t stream) {
    const int*   head     = (const int*)d_in[0];
    const int*   relation = (const int*)d_in[1];
    const int*   tail     = (const int*)d_in[2];
    const float* ent      = (const float*)d_in[3];
    const float* remb     = (const float*)d_in[4];
    const float* proj     = (const float*)d_in[5];
    float*       out      = (float*)d_out;

    dim3 grid(NCHUNK, NREL);
    transr_kernel<<<grid, 256, 0, stream>>>(head, relation, tail, ent, remb, proj, out);
}